// Round 3
// baseline (152.156 us; speedup 1.0000x reference)
//
#include <hip/hip_runtime.h>

#define LL   8192   // sequence length
#define CC   2048   // channels
#define FF   128    // inner dim of g@kernel
#define KK   257    // taps
#define PAD  128    // (KK-1)/2

#define XROW 8448   // padded xbp row: 128 zeros | 8192 data | 128 zeros
#define SROW 320    // synE row: 32 zeros | 257 taps | 31 zeros
#define NT   18     // K-steps of 16 -> covers K in [0,288)
#define SPLIT 2     // L-splits per channel (blocks), 4 tiles each
#define TILES 4     // (LL/1024)/SPLIT

typedef __bf16 bf16x8 __attribute__((ext_vector_type(8)));
typedef float  f32x16 __attribute__((ext_vector_type(16)));

static __device__ __forceinline__ unsigned short f2bf(float f) {
    unsigned u = __float_as_uint(f);
    u = (u + 0x7fffu + ((u >> 16) & 1u)) >> 16;   // RNE
    return (unsigned short)u;
}

// Build synEb[c][320] bf16: zeros | g[c,:]@kernel[:,k] | zeros, with the
// Yt-row override folded in as a delta kernel (tap=1 at k=128).
__global__ __launch_bounds__(256) void synb_kernel(const float* __restrict__ g,
                                                   const float* __restrict__ kern,
                                                   const int* __restrict__ Yt, int ny,
                                                   unsigned short* __restrict__ synEb) {
    __shared__ int sfl[4];
    const int c0 = blockIdx.x * 4;
    const int t  = threadIdx.x;
    if (t < 4) sfl[t] = 0;
    __syncthreads();
    for (int i = t; i < ny; i += 256) {
        int y = Yt[i];
        #pragma unroll
        for (int ii = 0; ii < 4; ++ii) if (y == c0 + ii) sfl[ii] = 1;
    }
    __syncthreads();
    const float* g0 = g + (size_t)(c0 + 0) * FF;
    const float* g1 = g + (size_t)(c0 + 1) * FF;
    const float* g2 = g + (size_t)(c0 + 2) * FF;
    const float* g3 = g + (size_t)(c0 + 3) * FF;
    const int fl0 = sfl[0], fl1 = sfl[1], fl2 = sfl[2], fl3 = sfl[3];
    for (int p = t; p < SROW; p += 256) {
        const int kk = p - 32;
        float a0 = 0.f, a1 = 0.f, a2 = 0.f, a3 = 0.f;
        const bool inr = (kk >= 0) && (kk < KK);
        if (inr) {
            #pragma unroll 8
            for (int f = 0; f < FF; ++f) {
                float kv = kern[f * KK + kk];      // coalesced across p
                a0 += kv * g0[f];
                a1 += kv * g1[f];
                a2 += kv * g2[f];
                a3 += kv * g3[f];
            }
        }
        float dlt = (kk == PAD) ? 1.f : 0.f;
        float v0 = inr ? (fl0 ? dlt : a0) : 0.f;
        float v1 = inr ? (fl1 ? dlt : a1) : 0.f;
        float v2 = inr ? (fl2 ? dlt : a2) : 0.f;
        float v3 = inr ? (fl3 ? dlt : a3) : 0.f;
        synEb[(size_t)(c0 + 0) * SROW + p] = f2bf(v0);
        synEb[(size_t)(c0 + 1) * SROW + p] = f2bf(v1);
        synEb[(size_t)(c0 + 2) * SROW + p] = f2bf(v2);
        synEb[(size_t)(c0 + 3) * SROW + p] = f2bf(v3);
    }
}

// x (L,C) fp32 -> xbp (C, XROW) bf16, transposed + zero-padded.
// Stores widened to ushort4 (8B/lane); LDS pad 65 keeps both phases 2-way-free.
__global__ __launch_bounds__(256) void xpose_kernel(const float* __restrict__ x,
                                                    unsigned short* __restrict__ xbp) {
    __shared__ float tile[64][65];
    const int l0 = blockIdx.x << 6;      // 128 blocks
    const int c0 = blockIdx.y << 6;      // 32 blocks
    const int t  = threadIdx.x;
    const int cl = t & 63, ls = t >> 6;
    #pragma unroll
    for (int k = 0; k < 16; ++k) {
        int ll = (k << 2) + ls;
        tile[ll][cl] = x[(size_t)(l0 + ll) * CC + c0 + cl];   // 256B/wave
    }
    __syncthreads();
    const int lw = (t & 15) << 2, cg = t >> 4;               // 4 l per thread
    #pragma unroll
    for (int k = 0; k < 4; ++k) {
        int cc = (k << 4) + cg;
        ushort4 v;
        v.x = f2bf(tile[lw + 0][cc]);    // bank (4a+d+cc)%32: 2-way, free
        v.y = f2bf(tile[lw + 1][cc]);
        v.z = f2bf(tile[lw + 2][cc]);
        v.w = f2bf(tile[lw + 3][cc]);
        *(ushort4*)(xbp + (size_t)(c0 + cc) * XROW + PAD + l0 + lw) = v;
    }
    if (blockIdx.x == 0) {               // fold pad zeroing into edge blocks
        for (int k = 0; k < 32; ++k) {
            int idx = (k << 8) + t, ch = idx >> 7, p = idx & 127;
            xbp[(size_t)(c0 + ch) * XROW + p] = 0;
        }
    } else if (blockIdx.x == 127) {
        for (int k = 0; k < 32; ++k) {
            int idx = (k << 8) + t, ch = idx >> 7, p = idx & 127;
            xbp[(size_t)(c0 + ch) * XROW + PAD + LL + p] = 0;
        }
    }
}

// Depthwise conv as Toeplitz MFMA. Wave = one channel x one L-half.
// BARRIER-FREE: every LDS region (xw[*][w], synL[w]) is wave-private, so
// same-wave in-order LDS semantics replace __syncthreads entirely — each
// wave is an independent 4-tile software pipeline (reg prefetch -> LDS dbuf).
__global__ __launch_bounds__(256, 3) void conv_mfma(const unsigned short* __restrict__ xbp,
                                                    const unsigned short* __restrict__ synEb,
                                                    float* __restrict__ out) {
    __shared__ int4 xw[2][4][192];            // 24.0 KB
    __shared__ unsigned short synL[4][SROW];  // 2.5 KB
    const int w  = threadIdx.x >> 6;
    const int ln = threadIdx.x & 63;
    const int sp = blockIdx.x;                // L-half
    const int c  = (blockIdx.y << 2) + w;
    const int j  = ln & 31;                   // A row i == D col == B col
    const int q  = ln >> 5;

    { // stage synE row (640 B, wave-private)
        const unsigned short* srow = synEb + (size_t)c * SROW;
        #pragma unroll
        for (int k = 0; k < 5; ++k) synL[w][ln + 64 * k] = srow[ln + 64 * k];
    }

    const unsigned short* xrow = xbp + (size_t)c * XROW + (size_t)(sp << 12);
    int4 st0, st1, st2;
    { // tile-0 staging: 160 granules = 1280-elem window
        const int4* src = (const int4*)xrow;
        st0 = src[ln];
        st1 = src[ln + 64];
        if (ln < 32) st2 = src[ln + 128];
        int g0 = ln,      s0 = g0 ^ ((g0 >> 3) & 7);
        int g1 = ln + 64, s1 = g1 ^ ((g1 >> 3) & 7);
        xw[0][w][s0] = st0;
        xw[0][w][s1] = st1;
        if (ln < 32) { int g2 = ln + 128, s2 = g2 ^ ((g2 >> 3) & 7); xw[0][w][s2] = st2; }
    }

    // B Toeplitz fragments: B[k=8q+r][j] = synE[16m + 8q + r - j]
    bf16x8 bfrag[NT];
    #pragma unroll
    for (int m = 0; m < NT; ++m) {
        union { unsigned short u[8]; bf16x8 v; } B;
        #pragma unroll
        for (int r = 0; r < 8; ++r)
            B.u[r] = synL[w][16 * m + 8 * q + r - j + 32];
        bfrag[m] = B.v;
    }

    const int gb = 4 * j + q;                 // A granule base
    float* orow = out + (size_t)c * (size_t)LL + (sp << 12) + j;

    for (int lt = 0; lt < TILES; ++lt) {
        const int buf = lt & 1;
        if (lt < TILES - 1) {                  // prefetch next window into regs
            const int4* src = (const int4*)(xrow + ((lt + 1) << 10));
            st0 = src[ln];
            st1 = src[ln + 64];
            if (ln < 32) st2 = src[ln + 128];
        }
        f32x16 acc;
        #pragma unroll
        for (int r = 0; r < 16; ++r) acc[r] = 0.0f;
        #pragma unroll
        for (int m = 0; m < NT; ++m) {
            int gm = gb + 2 * m;
            union { int4 i4; bf16x8 v; } A;
            A.i4 = xw[buf][w][gm ^ ((gm >> 3) & 7)];
            acc = __builtin_amdgcn_mfma_f32_32x32x16_bf16(A.v, bfrag[m], acc, 0, 0, 0);
        }
        float* o = orow + (lt << 10);
        #pragma unroll
        for (int r = 0; r < 16; ++r) {         // D: col=lane&31, row=(r&3)+8(r>>2)+4q
            int row = (r & 3) + ((r >> 2) << 3) + (q << 2);
            o[row << 5] = acc[r];
        }
        if (lt < TILES - 1) {                  // commit prefetch (WAR safe in-order)
            int g0 = ln,      s0 = g0 ^ ((g0 >> 3) & 7);
            int g1 = ln + 64, s1 = g1 ^ ((g1 >> 3) & 7);
            xw[buf ^ 1][w][s0] = st0;
            xw[buf ^ 1][w][s1] = st1;
            if (ln < 32) { int g2 = ln + 128, s2 = g2 ^ ((g2 >> 3) & 7); xw[buf ^ 1][w][s2] = st2; }
        }
    }
}

// ------------------------------------------------------------------- launch
extern "C" void kernel_launch(void* const* d_in, const int* in_sizes, int n_in,
                              void* d_out, int out_size, void* d_ws, size_t ws_size,
                              hipStream_t stream) {
    const float* x    = (const float*)d_in[0];
    const int*   Yt   = (const int*)  d_in[1];
    const float* g    = (const float*)d_in[2];
    const float* kern = (const float*)d_in[3];
    float* out = (float*)d_out;
    const int ny = in_sizes[1];

    const size_t xbp_bytes = (size_t)CC * XROW * sizeof(unsigned short); // 34.6 MB
    unsigned short* xbp   = (unsigned short*)d_ws;
    unsigned short* synEb = (unsigned short*)((char*)d_ws + xbp_bytes);  // +1.31 MB

    synb_kernel<<<CC / 4, 256, 0, stream>>>(g, kern, Yt, ny, synEb);
    xpose_kernel<<<dim3(LL / 64, CC / 64), 256, 0, stream>>>(x, xbp);
    conv_mfma<<<dim3(SPLIT, CC / 4), 256, 0, stream>>>(xbp, synEb, out);
}

// Round 5
// 147.803 us; speedup vs baseline: 1.0295x; 1.0295x over previous
//
#include <hip/hip_runtime.h>

#define LL   8192   // sequence length
#define CC   2048   // channels
#define FF   128    // inner dim of g@kernel
#define KK   257    // taps
#define PAD  128    // (KK-1)/2

#define SROW 320    // synEb row: 32 zeros | 257 taps | 31 zeros (u16 idx = k+32)
#define NT   18     // K-steps of 16 -> covers K in [0,288)

#define ROWS 1288   // xch LDS row in ushorts (2576 B: %16==0)
#define SRP  328    // synL LDS row in ushorts (656 B = 164 dwords; headroom for base+4 reads)

typedef __bf16 bf16x8 __attribute__((ext_vector_type(8)));
typedef float  f32x16 __attribute__((ext_vector_type(16)));

static __device__ __forceinline__ unsigned short f2bf(float f) {
    unsigned u = __float_as_uint(f);
    u = (u + 0x7fffu + ((u >> 16) & 1u)) >> 16;   // RNE
    return (unsigned short)u;
}

// Build synEb[c][320] bf16: zeros | g[c,:]@kernel[:,k] | zeros, with the
// Yt-row override folded in as a delta kernel (tap=1 at k=128) so the conv
// reproduces out[c,l] = x[l,c] exactly for flagged channels.
__global__ __launch_bounds__(256) void synb_kernel(const float* __restrict__ g,
                                                   const float* __restrict__ kern,
                                                   const int* __restrict__ Yt, int ny,
                                                   unsigned short* __restrict__ synEb) {
    __shared__ int sfl[4];
    const int c0 = blockIdx.x * 4;
    const int t  = threadIdx.x;
    if (t < 4) sfl[t] = 0;
    __syncthreads();
    for (int i = t; i < ny; i += 256) {
        int y = Yt[i];
        #pragma unroll
        for (int ii = 0; ii < 4; ++ii) if (y == c0 + ii) sfl[ii] = 1;
    }
    __syncthreads();
    const float* g0 = g + (size_t)(c0 + 0) * FF;
    const float* g1 = g + (size_t)(c0 + 1) * FF;
    const float* g2 = g + (size_t)(c0 + 2) * FF;
    const float* g3 = g + (size_t)(c0 + 3) * FF;
    const int fl0 = sfl[0], fl1 = sfl[1], fl2 = sfl[2], fl3 = sfl[3];
    for (int p = t; p < SROW; p += 256) {
        const int kk = p - 32;
        float a0 = 0.f, a1 = 0.f, a2 = 0.f, a3 = 0.f;
        const bool inr = (kk >= 0) && (kk < KK);
        if (inr) {
            #pragma unroll 8
            for (int f = 0; f < FF; ++f) {
                float kv = kern[f * KK + kk];      // coalesced across p
                a0 += kv * g0[f];
                a1 += kv * g1[f];
                a2 += kv * g2[f];
                a3 += kv * g3[f];
            }
        }
        float dlt = (kk == PAD) ? 1.f : 0.f;
        float v0 = inr ? (fl0 ? dlt : a0) : 0.f;
        float v1 = inr ? (fl1 ? dlt : a1) : 0.f;
        float v2 = inr ? (fl2 ? dlt : a2) : 0.f;
        float v3 = inr ? (fl3 ? dlt : a3) : 0.f;
        synEb[(size_t)(c0 + 0) * SROW + p] = f2bf(v0);
        synEb[(size_t)(c0 + 1) * SROW + p] = f2bf(v1);
        synEb[(size_t)(c0 + 2) * SROW + p] = f2bf(v2);
        synEb[(size_t)(c0 + 3) * SROW + p] = f2bf(v3);
    }
}

// Fused transpose + depthwise Toeplitz-MFMA conv.
// Block: 16 channels x 1024 outputs. Stage x[(L,C) fp32] -> LDS bf16 rows
// (XOR-granule-swizzled, same layout as the R2-verified reader), one barrier,
// then each wave MFMAs 4 channels (18 x mfma_f32_32x32x16_bf16 each).
__global__ __launch_bounds__(256) void fused_conv(const float* __restrict__ x,
                                                  const unsigned short* __restrict__ synEb,
                                                  float* __restrict__ out) {
    __shared__ alignas(16) unsigned short xch[16][ROWS];   // 41.2 KB
    __shared__ alignas(16) unsigned short synL[16][SRP];   // 10.5 KB
    const int t  = threadIdx.x;
    const int W0 = blockIdx.x << 10;          // window base (l of output 0)
    const int c0 = blockIdx.y << 4;

    // ---- stage syn rows (16 x 160 dwords, coalesced) ----
    {
        const int rw = t >> 4;                // 0..15 channel row
        const int u  = t & 15;
        const unsigned* src = (const unsigned*)(synEb + (size_t)(c0 + rw) * SROW);
        unsigned* dst = (unsigned*)(synL[rw]);
        #pragma unroll
        for (int k = 0; k < 10; ++k) dst[u + (k << 4)] = src[u + (k << 4)];
    }

    // ---- stage x window: logical p in [0,1280), xpad[p] = x[W0+p-128][c] ----
    #pragma unroll
    for (int k = 0; k < 10; ++k) {
        int pidx = (k << 8) + t;              // [0,2560)
        int ch4  = pidx & 3;                  // float4 channel quad
        int pp   = pidx >> 2;                 // dword (l-pair) index [0,640)
        int lg   = W0 + (pp << 1) - 128;      // global l of even element
        const float* sp = x + (size_t)lg * CC + c0 + (ch4 << 2);
        float4 ve = make_float4(0.f, 0.f, 0.f, 0.f);
        float4 vo = make_float4(0.f, 0.f, 0.f, 0.f);
        if ((unsigned)lg       < (unsigned)LL) ve = *(const float4*)sp;        // 16 segs/instr
        if ((unsigned)(lg + 1) < (unsigned)LL) vo = *(const float4*)(sp + CC);
        int gq = pp >> 2;                     // granule (8 u16)
        int gp = gq ^ ((gq >> 3) & 7);        // XOR swizzle (R2-verified)
        int dw = (gp << 2) | (pp & 3);        // dword slot within row
        const float* pe = (const float*)&ve;
        const float* po = (const float*)&vo;
        #pragma unroll
        for (int c2 = 0; c2 < 4; ++c2) {
            unsigned val = (unsigned)f2bf(pe[c2]) | ((unsigned)f2bf(po[c2]) << 16);
            ((unsigned*)xch[(ch4 << 2) + c2])[dw] = val;
        }
    }
    __syncthreads();

    const int w = t >> 6, ln = t & 63;
    const int j = ln & 31, q = ln >> 5;
    const int bb  = (q << 4) - 2 * j + 64;    // byte base of bfrag m=0 (in [2,80], even)
    const int dwb = bb >> 2;                  // dword base at m=0
    const int sh  = (bb & 2) << 3;            // residual funnel shift: 0 or 16 bits
    const int gb  = (j << 2) + q;             // A granule base

    for (int cc = 0; cc < 4; ++cc) {
        const int ci = (w << 2) + cc;
        // ---- bfrag build: 5 dwords + 64-bit funnel by sh (v_alignbit) ----
        // B.u[r] = synL[ci] u16 index (16m + 8q + r - j + 32); bytes [b, b+16),
        // b = 32m + bb. dword base = dwb + 8m; sh is m-invariant.
        bf16x8 bfrag[NT];
        const unsigned* rp = (const unsigned*)(synL[ci]);
        #pragma unroll
        for (int m = 0; m < NT; ++m) {
            int base = dwb + (m << 3);
            unsigned w0 = rp[base + 0], w1 = rp[base + 1], w2 = rp[base + 2],
                     w3 = rp[base + 3], w4 = rp[base + 4];
            union { unsigned d[4]; bf16x8 v; } B;
            B.d[0] = (unsigned)((((unsigned long long)w1 << 32) | w0) >> sh);
            B.d[1] = (unsigned)((((unsigned long long)w2 << 32) | w1) >> sh);
            B.d[2] = (unsigned)((((unsigned long long)w3 << 32) | w2) >> sh);
            B.d[3] = (unsigned)((((unsigned long long)w4 << 32) | w3) >> sh);
            bfrag[m] = B.v;
        }
        // ---- 18 MFMA over the Toeplitz K-extent ----
        f32x16 acc;
        #pragma unroll
        for (int r = 0; r < 16; ++r) acc[r] = 0.f;
        #pragma unroll
        for (int m = 0; m < NT; ++m) {
            int gq = gb + (m << 1);
            int gp = gq ^ ((gq >> 3) & 7);
            union { int4 i4; bf16x8 v; } A;
            A.i4 = *(const int4*)(&xch[ci][gp << 3]);
            acc = __builtin_amdgcn_mfma_f32_32x32x16_bf16(A.v, bfrag[m], acc, 0, 0, 0);
        }
        // ---- store: D col=lane&31, row=(r&3)+8*(r>>2)+4q ----
        float* o = out + (size_t)(c0 + ci) * LL + W0 + j;
        #pragma unroll
        for (int r = 0; r < 16; ++r) {
            int row = (r & 3) + ((r >> 2) << 3) + (q << 2);
            o[row << 5] = acc[r];             // 2 x 128B segments per instr
        }
    }
}

// ------------------------------------------------------------------- launch
extern "C" void kernel_launch(void* const* d_in, const int* in_sizes, int n_in,
                              void* d_out, int out_size, void* d_ws, size_t ws_size,
                              hipStream_t stream) {
    const float* x    = (const float*)d_in[0];
    const int*   Yt   = (const int*)  d_in[1];
    const float* g    = (const float*)d_in[2];
    const float* kern = (const float*)d_in[3];
    float* out = (float*)d_out;
    const int ny = in_sizes[1];

    unsigned short* synEb = (unsigned short*)d_ws;   // 2048*320*2 = 1.31 MB

    synb_kernel<<<CC / 4, 256, 0, stream>>>(g, kern, Yt, ny, synEb);
    fused_conv<<<dim3(LL / 1024, CC / 16), 256, 0, stream>>>(x, synEb, out);
}